// Round 7
// baseline (525.644 us; speedup 1.0000x reference)
//
#include <hip/hip_runtime.h>
#include <hip/hip_bf16.h>
#include <math.h>

// Problem constants
#define B_    64
#define MAXT  511
#define TP1   512
#define S_    1024
#define H_    4096
#define M_TOTAL (B_*TP1)   // 32768 rows
#define NITER (S_/32)      // 32 K-iterations

typedef __attribute__((ext_vector_type(8))) short  short8;   // 8 bf16 = 4 VGPRs (MFMA A/B frag)
typedef __attribute__((ext_vector_type(4))) float  float4v;  // MFMA C/D frag

// ---- workspace layout (bytes) ----
// zbuf [0, 512KB) -- Sb MUST start past it
#define ZBUF_BYTES ((size_t)M_TOTAL*4*sizeof(float))   // 524288
#define SBF_OFF    0x81000                             // 528384 >= ZBUF_BYTES
#define SBF_BYTES  ((size_t)M_TOTAL*S_*2)
#define W1T_OFF    (SBF_OFF + SBF_BYTES)

static __device__ __forceinline__ unsigned short f2bf(float f) {
    unsigned int u = __float_as_uint(f);
    u = u + 0x7fffu + ((u >> 16) & 1u);   // round-to-nearest-even
    return (unsigned short)(u >> 16);
}

// ---- merged pre-pass ----
// blocks [0,16384): s fp32 -> bf16, two live rows per block (wave-uniform skip)
// blocks [16384,16384+4096): W1 (S x H fp32) -> W1T (H x S bf16) 32x32 LDS transpose
// fp32 inputs read non-temporally: one-shot streams, keep Sb/W1T (~83 MB) in L3.
__global__ __launch_bounds__(256) void prep_kernel(const float* __restrict__ s,
                                                   const float* __restrict__ W1,
                                                   const int*   __restrict__ lengths,
                                                   unsigned short* __restrict__ Sb,
                                                   unsigned short* __restrict__ W1T) {
    int bid = blockIdx.x;
    if (bid < 16384) {
        int row = 2 * bid + (threadIdx.x >> 7);          // waves 0,1 -> row; waves 2,3 -> row+1
        int b = row >> 9, t = row & 511;
        if (t >= lengths[b]) return;                     // dead row: never read downstream
        size_t idx = (size_t)row * S_ + (threadIdx.x & 127) * 8;
        float4v f0 = __builtin_nontemporal_load((const float4v*)(s + idx));
        float4v f1 = __builtin_nontemporal_load((const float4v*)(s + idx + 4));
        short8 o;
        o[0] = (short)f2bf(f0[0]); o[1] = (short)f2bf(f0[1]);
        o[2] = (short)f2bf(f0[2]); o[3] = (short)f2bf(f0[3]);
        o[4] = (short)f2bf(f1[0]); o[5] = (short)f2bf(f1[1]);
        o[6] = (short)f2bf(f1[2]); o[7] = (short)f2bf(f1[3]);
        *(short8*)(Sb + idx) = o;
    } else {
        __shared__ float tile[32][33];
        int tb = bid - 16384;
        int h0 = (tb & 127) * 32;                        // H dim
        int k0 = (tb >> 7) * 32;                         // S dim
        int tx = threadIdx.x & 31, ty = threadIdx.x >> 5; // 32 x 8
        for (int r = ty; r < 32; r += 8)
            tile[r][tx] = __builtin_nontemporal_load(&W1[(size_t)(k0 + r) * H_ + h0 + tx]);
        __syncthreads();
        for (int r = ty; r < 32; r += 8)
            W1T[(size_t)(h0 + r) * S_ + k0 + tx] = f2bf(tile[tx][r]);
    }
}

// ---- main fused GEMM ----
// 128x128 tile, BK=32. Staging = buffer_load->VGPR->ds_write: register loads carry
// no LDS-visibility hazard, so barriers need no vmcnt drain; loads stay in flight
// across them. TWO register sets with EXPLICIT NAMES + manual x2 unroll: R4/R5's
// %3-indexed arrays got demoted to scratch (WRITE_SIZE 136 MB, VGPR=84); named
// sets are the proven spill-free form (R3: WRITE 43.5 MB, VGPR=96).
// XCD swizzle: xcd=id&7 owns ntiles [4x,4x+4) -> 1 MB W1T band stays L2-resident;
// 4 blocks sharing an A-tile sit on the same XCD.
__global__ __launch_bounds__(256) void gemm_fused_kernel(
        const unsigned short* __restrict__ Sb,    // M x S bf16
        const unsigned short* __restrict__ W1T,   // H x S bf16
        const float* __restrict__ b1,             // H
        const float* __restrict__ W2,             // H x 32 fp32 (cols 0..3 used)
        const int*   __restrict__ lengths,        // B
        float*       __restrict__ zbuf)           // M x 4
{
    int id   = blockIdx.x;
    int xcd  = id & 7;
    int slot = id >> 3;                  // 0..1023
    int ntile = xcd * 4 + (slot & 3);    // 0..31
    int mtile = slot >> 2;               // 0..255

    int b  = mtile >> 2;
    int t0 = (mtile & 3) * 128;
    if (lengths[b] <= t0) return;        // whole tile masked out

    int m0 = mtile * 128;
    int n0 = ntile * 128;

    __shared__ unsigned short smemA[2 * 128 * 32];   // 2 x 8 KB
    __shared__ unsigned short smemB[2 * 128 * 32];   // 2 x 8 KB

    int tid  = threadIdx.x;
    int wid  = tid >> 6;
    int lane = tid & 63;
    int lane15 = lane & 15;
    int quad   = lane >> 4;
    int wave_m = (wid >> 1) * 64;
    int wave_n = (wid & 1) * 64;

    // staging chunk map: chunk c -> row m=c>>2, slot cp=c&3, global k-chunk
    // q = cp ^ ((m>>1)&3)  (XOR swizzle -> 2-way-free LDS access)
    int cA0 = tid, cA1 = tid + 256;
    int mA0 = cA0 >> 2, cp0 = cA0 & 3, q0 = cp0 ^ ((mA0 >> 1) & 3);
    int mA1 = cA1 >> 2, cp1 = cA1 & 3, q1 = cp1 ^ ((mA1 >> 1) & 3);

    const char* gA0 = (const char*)Sb  + (size_t)(m0 + mA0) * (S_*2) + q0 * 16;
    const char* gA1 = (const char*)Sb  + (size_t)(m0 + mA1) * (S_*2) + q1 * 16;
    const char* gB0 = (const char*)W1T + (size_t)(n0 + mA0) * (S_*2) + q0 * 16;
    const char* gB1 = (const char*)W1T + (size_t)(n0 + mA1) * (S_*2) + q1 * 16;
    char* lwA0 = (char*)smemA + cA0 * 16;   // buf0 write addrs; buf1 = +8192
    char* lwA1 = (char*)smemA + cA1 * 16;
    char* lwB0 = (char*)smemB + cA0 * 16;
    char* lwB1 = (char*)smemB + cA1 * 16;

    // fragment read offsets within a buffer (in shorts)
    int aOff[4], bOff[4];
#pragma unroll
    for (int s = 0; s < 4; s++) {
        int ml = wave_m + s * 16 + lane15;
        aOff[s] = ml * 32 + (quad ^ ((ml >> 1) & 3)) * 8;
        int nl = wave_n + s * 16 + lane15;
        bOff[s] = nl * 32 + (quad ^ ((nl >> 1) & 3)) * 8;
    }

    float4v acc[4][4] = {};
    short8 rA0[2], rA1[2], rB0[2], rB1[2];   // register staging, 2 NAMED sets

    // ---- prologue: set0 = j=0 -> ds_write buf0; set1 = j=1 (in flight) ----
    rA0[0] = *(const short8*)gA0; rA1[0] = *(const short8*)gA1;
    rB0[0] = *(const short8*)gB0; rB1[0] = *(const short8*)gB1;
    gA0 += 64; gA1 += 64; gB0 += 64; gB1 += 64;
    *(short8*)lwA0 = rA0[0]; *(short8*)lwA1 = rA1[0];
    *(short8*)lwB0 = rB0[0]; *(short8*)lwB1 = rB1[0];
    rA0[1] = *(const short8*)gA0; rA1[1] = *(const short8*)gA1;
    rB0[1] = *(const short8*)gB0; rB1[1] = *(const short8*)gB1;
    gA0 += 64; gA1 += 64; gB0 += 64; gB1 += 64;

    for (int k = 0; k < NITER; k += 2) {
        // ---- even sub-iter: compute buf0 (j=k), write set1 (j=k+1) -> buf1,
        //      load set0 <- j=k+2
        __syncthreads();
        if (k + 2 < NITER) {
            rA0[0] = *(const short8*)gA0; rA1[0] = *(const short8*)gA1;
            rB0[0] = *(const short8*)gB0; rB1[0] = *(const short8*)gB1;
            gA0 += 64; gA1 += 64; gB0 += 64; gB1 += 64;
        }
        *(short8*)(lwA0 + 8192) = rA0[1]; *(short8*)(lwA1 + 8192) = rA1[1];
        *(short8*)(lwB0 + 8192) = rB0[1]; *(short8*)(lwB1 + 8192) = rB1[1];
        {
            const unsigned short* aP = smemA;
            const unsigned short* bP = smemB;
            short8 af[4], bf[4];
#pragma unroll
            for (int s = 0; s < 4; s++) {
                af[s] = *(const short8*)(aP + aOff[s]);
                bf[s] = *(const short8*)(bP + bOff[s]);
            }
#pragma unroll
            for (int i = 0; i < 4; i++)
#pragma unroll
                for (int j = 0; j < 4; j++)
                    acc[i][j] = __builtin_amdgcn_mfma_f32_16x16x32_bf16(af[i], bf[j], acc[i][j], 0, 0, 0);
        }
        // ---- odd sub-iter: compute buf1 (j=k+1), write set0 (j=k+2) -> buf0,
        //      load set1 <- j=k+3
        __syncthreads();
        if (k + 3 < NITER) {
            rA0[1] = *(const short8*)gA0; rA1[1] = *(const short8*)gA1;
            rB0[1] = *(const short8*)gB0; rB1[1] = *(const short8*)gB1;
            gA0 += 64; gA1 += 64; gB0 += 64; gB1 += 64;
        }
        if (k + 2 < NITER) {
            *(short8*)lwA0 = rA0[0]; *(short8*)lwA1 = rA1[0];
            *(short8*)lwB0 = rB0[0]; *(short8*)lwB1 = rB1[0];
        }
        {
            const unsigned short* aP = smemA + 4096;
            const unsigned short* bP = smemB + 4096;
            short8 af[4], bf[4];
#pragma unroll
            for (int s = 0; s < 4; s++) {
                af[s] = *(const short8*)(aP + aOff[s]);
                bf[s] = *(const short8*)(bP + bOff[s]);
            }
#pragma unroll
            for (int i = 0; i < 4; i++)
#pragma unroll
                for (int j = 0; j < 4; j++)
                    acc[i][j] = __builtin_amdgcn_mfma_f32_16x16x32_bf16(af[i], bf[j], acc[i][j], 0, 0, 0);
        }
    }

    // ---- fused epilogue: relu(h) @ W2[:,0:4], shuffle-reduce, atomicAdd ----
    float4v w2r[4];
    float   b1v[4];
#pragma unroll
    for (int ns = 0; ns < 4; ns++) {
        int n_g = n0 + wave_n + ns * 16 + lane15;
        w2r[ns] = *(const float4v*)(W2 + (size_t)n_g * 32);
        b1v[ns] = b1[n_g];
    }
#pragma unroll
    for (int ms = 0; ms < 4; ms++) {
        float p[4][4];
#pragma unroll
        for (int r = 0; r < 4; r++)
#pragma unroll
            for (int c = 0; c < 4; c++) p[r][c] = 0.f;
#pragma unroll
        for (int ns = 0; ns < 4; ns++) {
            float4v av = acc[ms][ns];
#pragma unroll
            for (int r = 0; r < 4; r++) {
                float h = av[r] + b1v[ns];
                h = h > 0.f ? h : 0.f;
                p[r][0] += h * w2r[ns][0];
                p[r][1] += h * w2r[ns][1];
                p[r][2] += h * w2r[ns][2];
                p[r][3] += h * w2r[ns][3];
            }
        }
#pragma unroll
        for (int off = 1; off < 16; off <<= 1)
#pragma unroll
            for (int r = 0; r < 4; r++)
#pragma unroll
                for (int c = 0; c < 4; c++)
                    p[r][c] += __shfl_xor(p[r][c], off);
        if (lane15 < 4) {
            int c = lane15;
#pragma unroll
            for (int r = 0; r < 4; r++) {
                int mg = m0 + wave_m + ms * 16 + quad * 4 + r;
                atomicAdd(&zbuf[(size_t)mg * 4 + c], p[r][c]);
            }
        }
    }
}

// ---- log-softmax gather + masked sum straight into d_out (zeroed beforehand) ----
__global__ __launch_bounds__(128) void reduce_logp_kernel(
        const float* __restrict__ zbuf,
        const int*   __restrict__ actions,
        const int*   __restrict__ lengths,
        const float* __restrict__ b2,
        float*       __restrict__ out)
{
    int b = blockIdx.x;
    int t = blockIdx.y * 128 + threadIdx.x;
    int len = lengths[b];
    float local = 0.f;
    if (t < MAXT && t < len) {
        int row = b * TP1 + t;
        float4v z = *(const float4v*)(zbuf + (size_t)row * 4);
        float z0 = z[0] + b2[0], z1 = z[1] + b2[1], z2 = z[2] + b2[2], z3 = z[3] + b2[3];
        float mx = fmaxf(fmaxf(z0, z1), fmaxf(z2, z3));
        float se = expf(z0 - mx) + expf(z1 - mx) + expf(z2 - mx) + expf(z3 - mx);
        int a = actions[b * MAXT + t];
        float za = (a == 0) ? z0 : (a == 1) ? z1 : (a == 2) ? z2 : z3;
        local = (za - mx) - logf(se);
    }
#pragma unroll
    for (int off = 32; off > 0; off >>= 1) local += __shfl_xor(local, off);
    __shared__ float wsum[2];
    if ((threadIdx.x & 63) == 0) wsum[threadIdx.x >> 6] = local;
    __syncthreads();
    if (threadIdx.x == 0) atomicAdd(out, -(wsum[0] + wsum[1]));   // negate here: out = -sum(logp)
}

extern "C" void kernel_launch(void* const* d_in, const int* in_sizes, int n_in,
                              void* d_out, int out_size, void* d_ws, size_t ws_size,
                              hipStream_t stream) {
    const float* s       = (const float*)d_in[0];  // (64,512,1024) fp32
    const int*   actions = (const int*)  d_in[1];  // (64,511)
    const int*   lengths = (const int*)  d_in[2];  // (64,)
    const float* W1      = (const float*)d_in[3];  // (1024,4096)
    const float* b1      = (const float*)d_in[4];  // (4096,)
    const float* W2      = (const float*)d_in[5];  // (4096,32)
    const float* b2      = (const float*)d_in[6];  // (32,)

    char* ws = (char*)d_ws;
    float*          zbuf = (float*)ws;             // [0, 512KB)
    unsigned short* Sb   = (unsigned short*)(ws + SBF_OFF);
    unsigned short* W1T  = (unsigned short*)(ws + W1T_OFF);

    // zero z-buffer and output accumulator (ws/out poisoned 0xAA before every launch)
    hipMemsetAsync(ws, 0, ZBUF_BYTES, stream);
    hipMemsetAsync(d_out, 0, sizeof(float), stream);

    // merged pre-pass: s->bf16 (live rows, nt loads) + W1->W1T bf16
    prep_kernel<<<dim3(16384 + 4096), 256, 0, stream>>>(s, W1, lengths, Sb, W1T);
    // fused GEMM + relu + W2[:,0:4] projection (XCD-swizzled 1D grid)
    gemm_fused_kernel<<<dim3(8192), 256, 0, stream>>>(Sb, W1T, b1, W2, lengths, zbuf);
    // log-softmax gather + masked sum -> d_out
    reduce_logp_kernel<<<dim3(B_, 4), 128, 0, stream>>>(zbuf, actions, lengths, b2, (float*)d_out);
}